// Round 13
// baseline (67.658 us; speedup 1.0000x reference)
//
#include <hip/hip_runtime.h>

// Lovasz-Softmax without sorting (exact up to bin-midpoint error <= 0.5/NB):
//  - ties in the error don't change the loss (telescoping within equal-error
//    groups); jaccard is monotone with total variation 1 -> binning to NB bins
//    with midpoints has per-class error <= 0.5/NB (7.8e-3 at NB=64 vs 1.67e-2
//    threshold; measured absmax 0.0 at NB=64/128/256 - midpoint errors cancel).
// R13 = R12 (23.85us) minus the zero kernel and minus ALL global atomics:
//  - hist block b writes its complete 768-word histogram to private region
//    ghist[b*768 ..] with plain stores (every word written -> no pre-zero).
//  - scanfinal sums the 512 regions (1.5MB, L2-resident, coalesced).
//  - 2 dispatches. Cross-kernel visibility = standard end-of-dispatch release
//    (same mechanism all previous passing rounds relied on).

constexpr int NCLS = 6;
constexpr int HW   = 512 * 512;
constexpr int NPIX = 8 * HW;
constexpr int NB   = 64;         // bin width 1/64 -> loss error <= 7.8e-3
constexpr int NROWS = 2 * NCLS;  // rows 0..5: non-fg (p_c); 6..11: fg (1-p_lab)
constexpr int HIST_WORDS = NROWS * NB;     // 768
constexpr int NSUB = 16;
constexpr int SUBSTRIDE = HIST_WORDS + 8;  // 776; %32==8 -> bank-shifted copies

constexpr int HBLK = 512;        // 1 quad per thread exactly
constexpr int HTHR = 1024;

__global__ __launch_bounds__(HTHR) void lovasz_hist(
    const float* __restrict__ logits, const int* __restrict__ labels,
    unsigned* __restrict__ ghist) {
  __shared__ unsigned lh[NSUB * SUBSTRIDE];  // ~48.5 KB
  for (int i = threadIdx.x; i < NSUB * SUBSTRIDE; i += HTHR) lh[i] = 0u;
  __syncthreads();

  const int sub = (threadIdx.x & 15) * SUBSTRIDE;   // 4 lanes per copy
  const int q  = blockIdx.x * HTHR + threadIdx.x;   // 0 .. 524287
  const int n4 = q << 2;
  const int b  = n4 >> 18;                   // / HW
  const int hw = n4 & (HW - 1);

  int4 lab4 = *reinterpret_cast<const int4*>(labels + n4);
  int labs[4] = {lab4.x, lab4.y, lab4.z, lab4.w};
  if ((lab4.x | lab4.y | lab4.z | lab4.w) != 0) {   // else all ignored: skip
    float xx[NCLS][4];
    size_t base = ((size_t)b * NCLS) << 18;
#pragma unroll
    for (int c = 0; c < NCLS; ++c) {
      float4 v = *reinterpret_cast<const float4*>(logits + base + ((size_t)c << 18) + hw);
      xx[c][0] = v.x; xx[c][1] = v.y; xx[c][2] = v.z; xx[c][3] = v.w;
    }

#pragma unroll
    for (int j = 0; j < 4; ++j) {
      int lab = labs[j];
      if (lab == 0) continue;                // IGNORE: contributes exactly 0
      float m = xx[0][j];
#pragma unroll
      for (int c = 1; c < NCLS; ++c) m = fmaxf(m, xx[c][j]);
      float e[NCLS];
      float s = 0.f;
#pragma unroll
      for (int c = 0; c < NCLS; ++c) { e[c] = __expf(xx[c][j] - m); s += e[c]; }
      float inv = 1.0f / s;
#pragma unroll
      for (int c = 0; c < NCLS; ++c) {
        float p   = e[c] * inv;
        bool  fg  = (c == lab);
        float err = fg ? 1.0f - p : p;
        int bin = (int)(err * (float)NB);
        bin = bin < 0 ? 0 : (bin > NB - 1 ? NB - 1 : bin);
        int row = fg ? NCLS + c : c;
        atomicAdd(&lh[sub + row * NB + bin], 1u);
      }
    }
  }

  __syncthreads();
  // private region, plain stores, every word written
  unsigned* gbase = ghist + (size_t)blockIdx.x * HIST_WORDS;
  for (int i = threadIdx.x; i < HIST_WORDS; i += HTHR) {
    unsigned v = 0;
#pragma unroll
    for (int k = 0; k < NSUB; ++k) v += lh[k * SUBSTRIDE + i];
    gbase[i] = v;
  }
}

// One block, 6 waves: wave w handles class w. Each lane owns 1 bin;
// lane 0 has the highest-error bin so lane order == descending order.
// Sums the 512 per-block regions first (L2-resident, coalesced).
__global__ __launch_bounds__(64 * NCLS) void lovasz_scanfinal(
    const unsigned* __restrict__ ghist, float* __restrict__ out) {
  const int wave = threadIdx.x >> 6;       // class index
  const int lane = threadIdx.x & 63;
  const int bidx = NB - 1 - lane;          // lane 0 -> highest bin

  unsigned a = 0, f = 0;
#pragma unroll 8
  for (int r = 0; r < HBLK; ++r) {
    a += ghist[(size_t)r * HIST_WORDS + wave * NB + bidx];
    f += ghist[(size_t)r * HIST_WORDS + (NCLS + wave) * NB + bidx];
  }

  unsigned dn = a + f, df = f;
  unsigned sn = dn, sf = df;               // inclusive wave scan
  for (int off = 1; off < 64; off <<= 1) {
    unsigned tn = __shfl_up(sn, off);
    unsigned tf = __shfl_up(sf, off);
    if (lane >= off) { sn += tn; sf += tf; }
  }
  const unsigned total_f = __shfl(sf, 63); // gts
  const unsigned n0 = sn - dn;             // exclusive prefix (larger errors)
  const unsigned f0 = sf - df;

  double contrib = 0.0;
  if (total_f > 0 && dn) {
    const double gts = (double)total_f;
    double ub = gts + (double)n0 - (double)f0;
    double jb = 1.0 - (gts - (double)f0) / ub;
    double ua = gts + (double)sn - (double)sf;
    double ja = 1.0 - (gts - (double)sf) / ua;
    contrib = ((double)bidx + 0.5) * (1.0 / (double)NB) * (ja - jb);
  }
  for (int off = 32; off > 0; off >>= 1) contrib += __shfl_down(contrib, off);

  __shared__ double   sloss[NCLS];
  __shared__ unsigned spres[NCLS];
  if (lane == 0) { sloss[wave] = contrib; spres[wave] = total_f; }
  __syncthreads();
  if (threadIdx.x == 0) {
    double s = 0.0, np = 0.0;
    for (int k = 0; k < NCLS; ++k)
      if (spres[k]) { s += sloss[k]; np += 1.0; }
    out[0] = (float)(s / (np > 0.0 ? np : 1.0));
  }
}

extern "C" void kernel_launch(void* const* d_in, const int* in_sizes, int n_in,
                              void* d_out, int out_size, void* d_ws, size_t ws_size,
                              hipStream_t stream) {
  const float* logits = (const float*)d_in[0];
  const int*   labels = (const int*)d_in[1];
  unsigned*    ghist  = (unsigned*)d_ws;   // 512 * 768 words = 1.5 MB

  lovasz_hist<<<HBLK, HTHR, 0, stream>>>(logits, labels, ghist);
  lovasz_scanfinal<<<1, 64 * NCLS, 0, stream>>>(ghist, (float*)d_out);
}

// Round 14
// 24.371 us; speedup vs baseline: 2.7762x; 2.7762x over previous
//
#include <hip/hip_runtime.h>

// Lovasz-Softmax without sorting (exact up to bin-midpoint error <= 0.5/NB):
//  - ties in the error don't change the loss (telescoping within equal-error
//    groups); jaccard is monotone with total variation 1 -> binning to NB bins
//    with midpoints has per-class error <= 0.5/NB (7.8e-3 at NB=64 vs 1.67e-2
//    threshold; measured absmax 0.0 at NB=64/128/256 - midpoint errors cancel).
// R14 = exact revert to R12 (best measured: 23.85us).
// Ledger of failed alternatives: coop grid.sync (92us), spin-flag 1-dispatch
// (103us), fenced ticket (175us), fence-free ticket 2-dispatch (27us),
// private-region stores + single-block 1.5MB reduce (68us, latency-bound).
// Structure: zero(6KB) -> hist(512x1024, 16 LDS sub-hists, 8-region atomic
// flush) -> scanfinal(1 block, 6 waves). 3 dispatches.

constexpr int NCLS = 6;
constexpr int HW   = 512 * 512;
constexpr int NPIX = 8 * HW;
constexpr int NB   = 64;         // bin width 1/64 -> loss error <= 7.8e-3
constexpr int NROWS = 2 * NCLS;  // rows 0..5: non-fg (p_c); 6..11: fg (1-p_lab)
constexpr int HIST_WORDS = NROWS * NB;     // 768
constexpr int NSUB = 16;
constexpr int SUBSTRIDE = HIST_WORDS + 8;  // 776; %32==8 -> bank-shifted copies
constexpr int NREG = 8;                    // global flush regions
constexpr int GHIST_WORDS = NREG * HIST_WORDS;  // 6144

constexpr int HBLK = 512;        // 1 quad per thread exactly
constexpr int HTHR = 1024;

__global__ __launch_bounds__(1024) void lovasz_zero(unsigned* __restrict__ g) {
  int i = blockIdx.x * 1024 + threadIdx.x;
  if (i < GHIST_WORDS) g[i] = 0u;
}

__global__ __launch_bounds__(HTHR) void lovasz_hist(
    const float* __restrict__ logits, const int* __restrict__ labels,
    unsigned* __restrict__ ghist) {
  __shared__ unsigned lh[NSUB * SUBSTRIDE];  // ~48.5 KB
  for (int i = threadIdx.x; i < NSUB * SUBSTRIDE; i += HTHR) lh[i] = 0u;
  __syncthreads();

  const int sub = (threadIdx.x & 15) * SUBSTRIDE;   // 4 lanes per copy
  const int q  = blockIdx.x * HTHR + threadIdx.x;   // 0 .. 524287
  const int n4 = q << 2;
  const int b  = n4 >> 18;                   // / HW
  const int hw = n4 & (HW - 1);

  int4 lab4 = *reinterpret_cast<const int4*>(labels + n4);
  int labs[4] = {lab4.x, lab4.y, lab4.z, lab4.w};
  if ((lab4.x | lab4.y | lab4.z | lab4.w) != 0) {   // else all ignored: skip
    float xx[NCLS][4];
    size_t base = ((size_t)b * NCLS) << 18;
#pragma unroll
    for (int c = 0; c < NCLS; ++c) {
      float4 v = *reinterpret_cast<const float4*>(logits + base + ((size_t)c << 18) + hw);
      xx[c][0] = v.x; xx[c][1] = v.y; xx[c][2] = v.z; xx[c][3] = v.w;
    }

#pragma unroll
    for (int j = 0; j < 4; ++j) {
      int lab = labs[j];
      if (lab == 0) continue;                // IGNORE: contributes exactly 0
      float m = xx[0][j];
#pragma unroll
      for (int c = 1; c < NCLS; ++c) m = fmaxf(m, xx[c][j]);
      float e[NCLS];
      float s = 0.f;
#pragma unroll
      for (int c = 0; c < NCLS; ++c) { e[c] = __expf(xx[c][j] - m); s += e[c]; }
      float inv = 1.0f / s;
#pragma unroll
      for (int c = 0; c < NCLS; ++c) {
        float p   = e[c] * inv;
        bool  fg  = (c == lab);
        float err = fg ? 1.0f - p : p;
        int bin = (int)(err * (float)NB);
        bin = bin < 0 ? 0 : (bin > NB - 1 ? NB - 1 : bin);
        int row = fg ? NCLS + c : c;
        atomicAdd(&lh[sub + row * NB + bin], 1u);
      }
    }
  }

  __syncthreads();
  unsigned* gbase = ghist + (blockIdx.x & (NREG - 1)) * HIST_WORDS;
  for (int i = threadIdx.x; i < HIST_WORDS; i += HTHR) {
    unsigned v = 0;
#pragma unroll
    for (int k = 0; k < NSUB; ++k) v += lh[k * SUBSTRIDE + i];
    if (v) atomicAdd(&gbase[i], v);
  }
}

// One block, 6 waves: wave w handles class w. Each lane owns 1 bin;
// lane 0 has the highest-error bin so lane order == descending order.
__global__ __launch_bounds__(64 * NCLS) void lovasz_scanfinal(
    const unsigned* __restrict__ ghist, float* __restrict__ out) {
  const int wave = threadIdx.x >> 6;       // class index
  const int lane = threadIdx.x & 63;
  const int bidx = NB - 1 - lane;          // lane 0 -> highest bin

  unsigned a = 0, f = 0;
#pragma unroll
  for (int r = 0; r < NREG; ++r) {
    a += ghist[r * HIST_WORDS + wave * NB + bidx];
    f += ghist[r * HIST_WORDS + (NCLS + wave) * NB + bidx];
  }

  unsigned dn = a + f, df = f;
  unsigned sn = dn, sf = df;               // inclusive wave scan
  for (int off = 1; off < 64; off <<= 1) {
    unsigned tn = __shfl_up(sn, off);
    unsigned tf = __shfl_up(sf, off);
    if (lane >= off) { sn += tn; sf += tf; }
  }
  const unsigned total_f = __shfl(sf, 63); // gts
  const unsigned n0 = sn - dn;             // exclusive prefix (larger errors)
  const unsigned f0 = sf - df;

  double contrib = 0.0;
  if (total_f > 0 && dn) {
    const double gts = (double)total_f;
    double ub = gts + (double)n0 - (double)f0;
    double jb = 1.0 - (gts - (double)f0) / ub;
    double ua = gts + (double)sn - (double)sf;
    double ja = 1.0 - (gts - (double)sf) / ua;
    contrib = ((double)bidx + 0.5) * (1.0 / (double)NB) * (ja - jb);
  }
  for (int off = 32; off > 0; off >>= 1) contrib += __shfl_down(contrib, off);

  __shared__ double   sloss[NCLS];
  __shared__ unsigned spres[NCLS];
  if (lane == 0) { sloss[wave] = contrib; spres[wave] = total_f; }
  __syncthreads();
  if (threadIdx.x == 0) {
    double s = 0.0, np = 0.0;
    for (int k = 0; k < NCLS; ++k)
      if (spres[k]) { s += sloss[k]; np += 1.0; }
    out[0] = (float)(s / (np > 0.0 ? np : 1.0));
  }
}

extern "C" void kernel_launch(void* const* d_in, const int* in_sizes, int n_in,
                              void* d_out, int out_size, void* d_ws, size_t ws_size,
                              hipStream_t stream) {
  const float* logits = (const float*)d_in[0];
  const int*   labels = (const int*)d_in[1];
  unsigned*    ghist  = (unsigned*)d_ws;

  lovasz_zero<<<(GHIST_WORDS + 1023) / 1024, 1024, 0, stream>>>(ghist);
  lovasz_hist<<<HBLK, HTHR, 0, stream>>>(logits, labels, ghist);
  lovasz_scanfinal<<<1, 64 * NCLS, 0, stream>>>(ghist, (float*)d_out);
}